// Round 1
// baseline (900.269 us; speedup 1.0000x reference)
//
#include <hip/hip_runtime.h>

// ---------------------------------------------------------------------------
// Routed top-2 MoE for MI355X (gfx950).
// Pipeline:
//   1. cast x -> xh/xl bf16 split (for high-precision routing GEMM)
//   2. transpose-precast all weights to bf16 [N][K] (w_route also split h/l)
//   3. routing GEMM: acts = x @ w_route  (3-term bf16-split MFMA, fp32 norms)
//   4. router: softmax, top-2, combine weights, counts, prob sums
//   5. plan: prefix sums -> per-expert tile map; bl_loss
//   6. fill: per-(slot,expert) token lists
//   7. per slot: GEMM1 (gathered x@w3 * silu(acts@wr2h) -> h bf16)
//               GEMM2 (h@wh2d * topw -> out; slot0 stores, slot1 adds)
// All GEMMs: 128x128x(BK=64) tiles, 4 waves, 16x16x32 bf16 MFMA,
// global_load_lds(16B) staging with pre-swizzled source (XOR (row&7)<<4).
// ---------------------------------------------------------------------------

#define DEV static __device__ __forceinline__

typedef float  f32x4  __attribute__((ext_vector_type(4)));
typedef __bf16 bf16x8 __attribute__((ext_vector_type(8)));

DEV unsigned short f2bf(float f) {
  union { float f; unsigned u; } v; v.f = f;
  unsigned r = v.u + 0x7fffu + ((v.u >> 16) & 1u);   // RNE
  return (unsigned short)(r >> 16);
}
DEV float bf2f(unsigned short b) {
  union { unsigned u; float f; } v; v.u = ((unsigned)b) << 16;
  return v.f;
}

DEV void gll16(const void* g, void* l) {
  __builtin_amdgcn_global_load_lds(
      (const __attribute__((address_space(1))) unsigned int*)g,
      (__attribute__((address_space(3))) unsigned int*)l, 16, 0, 0);
}

DEV f32x4 mfma16(bf16x8 a, bf16x8 b, f32x4 c) {
  return __builtin_amdgcn_mfma_f32_16x16x32_bf16(a, b, c, 0, 0, 0);
}

// Stage a [128][BK=64] bf16 tile into linear LDS; source 16B blocks XOR-
// swizzled by (row&7) so that swizzled frag reads hit spread banks.
DEV void stage_linear(const unsigned short* base, size_t pitch, int k0,
                      unsigned short* lds, int tid) {
  int wq = tid >> 6, lane = tid & 63;
#pragma unroll
  for (int i = 0; i < 4; ++i) {
    int s = wq * 256 + i * 64 + lane;     // 16B slot id, 1024 slots total
    int row = s >> 3, b = s & 7;
    int bb = b ^ (row & 7);
    const unsigned short* g = base + (size_t)row * pitch + (size_t)(k0 + bb * 8);
    gll16(g, lds + (size_t)(wq * 256 + i * 64) * 8);
  }
}

// Same, but row -> token gather through a shared-memory token list.
DEV void stage_gather(const unsigned short* base, size_t pitch, size_t colOff,
                      int k0, const int* toks, unsigned short* lds, int tid) {
  int wq = tid >> 6, lane = tid & 63;
#pragma unroll
  for (int i = 0; i < 4; ++i) {
    int s = wq * 256 + i * 64 + lane;
    int row = s >> 3, b = s & 7;
    int bb = b ^ (row & 7);
    const unsigned short* g =
        base + (size_t)toks[row] * pitch + colOff + (size_t)(k0 + bb * 8);
    gll16(g, lds + (size_t)(wq * 256 + i * 64) * 8);
  }
}

// Read one bf16x8 fragment (row, k in [kb, kb+8)) from a swizzled tile.
DEV bf16x8 frag_read(const unsigned short* lds, int row, int kb) {
  int off = row * 128 + ((kb * 2) ^ ((row & 7) << 4));
  return *(const bf16x8*)((const char*)lds + off);
}

// One BK=64 step of 16 MFMAs per wave into a 4x4 accumulator.
DEV void mfma_block(const unsigned short* A, const unsigned short* B,
                    f32x4 (&acc)[4][4], int wm, int wn, int lg, int lc) {
#pragma unroll
  for (int ks = 0; ks < 2; ++ks) {
    int kb = ks * 32 + lg * 8;
    bf16x8 af[4], bff[4];
#pragma unroll
    for (int i = 0; i < 4; ++i) {
      af[i]  = frag_read(A, wm * 64 + i * 16 + lc, kb);
      bff[i] = frag_read(B, wn * 64 + i * 16 + lc, kb);
    }
#pragma unroll
    for (int mf = 0; mf < 4; ++mf)
#pragma unroll
      for (int nf = 0; nf < 4; ++nf)
        acc[mf][nf] = mfma16(af[mf], bff[nf], acc[mf][nf]);
  }
}

// ---------------------------------------------------------------------------

__global__ __launch_bounds__(256) void k_cast_x(const float* __restrict__ x,
    unsigned short* __restrict__ xh, unsigned short* __restrict__ xl) {
  int stride = gridDim.x * blockDim.x;
  for (int i = blockIdx.x * blockDim.x + threadIdx.x; i < 8192 * 1024 / 4;
       i += stride) {
    float4 v = ((const float4*)x)[i];
    ushort4 h, l;
    h.x = f2bf(v.x); l.x = f2bf(v.x - bf2f(h.x));
    h.y = f2bf(v.y); l.y = f2bf(v.y - bf2f(h.y));
    h.z = f2bf(v.z); l.z = f2bf(v.z - bf2f(h.z));
    h.w = f2bf(v.w); l.w = f2bf(v.w - bf2f(h.w));
    ((ushort4*)xh)[i] = h;
    ((ushort4*)xl)[i] = l;
  }
}

__global__ void k_zero(int* cnt, float* probsum) {
  int t = threadIdx.x;
  if (t < 16) cnt[t] = 0;
  if (t < 8)  probsum[t] = 0.f;
}

// Transpose fp32 [E][K][N] -> bf16 [E][N][K] via 64x64 LDS tiles.
__global__ __launch_bounds__(256) void k_transp(const float* __restrict__ src,
    unsigned short* __restrict__ dst, int K, int N) {
  int ntn = N >> 6;
  int kt = blockIdx.x / ntn, nt = blockIdx.x % ntn;
  int e = blockIdx.y;
  __shared__ float tl[64][65];
  const float* s = src + (size_t)e * K * N;
  unsigned short* d = dst + (size_t)e * N * K;
  int tid = threadIdx.x;
  int c4 = (tid & 15) * 4, rr = tid >> 4;
#pragma unroll
  for (int p = 0; p < 4; ++p) {
    int row = rr + p * 16;
    float4 v = *(const float4*)(s + (size_t)(kt * 64 + row) * N + nt * 64 + c4);
    tl[row][c4] = v.x; tl[row][c4 + 1] = v.y;
    tl[row][c4 + 2] = v.z; tl[row][c4 + 3] = v.w;
  }
  __syncthreads();
#pragma unroll
  for (int p = 0; p < 4; ++p) {
    int n = rr + p * 16;
    ushort4 o;
    o.x = f2bf(tl[c4 + 0][n]); o.y = f2bf(tl[c4 + 1][n]);
    o.z = f2bf(tl[c4 + 2][n]); o.w = f2bf(tl[c4 + 3][n]);
    *(ushort4*)(d + (size_t)(nt * 64 + n) * K + kt * 64 + c4) = o;
  }
}

// Same transpose but emits hi/lo bf16 split (for w_route).
__global__ __launch_bounds__(256) void k_transp_split(const float* __restrict__ src,
    unsigned short* __restrict__ dh, unsigned short* __restrict__ dl, int K, int N) {
  int ntn = N >> 6;
  int kt = blockIdx.x / ntn, nt = blockIdx.x % ntn;
  int e = blockIdx.y;
  __shared__ float tl[64][65];
  const float* s = src + (size_t)e * K * N;
  size_t dbase = (size_t)e * N * K;
  int tid = threadIdx.x;
  int c4 = (tid & 15) * 4, rr = tid >> 4;
#pragma unroll
  for (int p = 0; p < 4; ++p) {
    int row = rr + p * 16;
    float4 v = *(const float4*)(s + (size_t)(kt * 64 + row) * N + nt * 64 + c4);
    tl[row][c4] = v.x; tl[row][c4 + 1] = v.y;
    tl[row][c4 + 2] = v.z; tl[row][c4 + 3] = v.w;
  }
  __syncthreads();
#pragma unroll
  for (int p = 0; p < 4; ++p) {
    int n = rr + p * 16;
    ushort4 oh, ol;
#pragma unroll
    for (int i = 0; i < 4; ++i) {
      float v = tl[c4 + i][n];
      unsigned short hh = f2bf(v);
      unsigned short ll = f2bf(v - bf2f(hh));
      ((unsigned short*)&oh)[i] = hh;
      ((unsigned short*)&ol)[i] = ll;
    }
    *(ushort4*)(dh + dbase + (size_t)(nt * 64 + n) * K + kt * 64 + c4) = oh;
    *(ushort4*)(dl + dbase + (size_t)(nt * 64 + n) * K + kt * 64 + c4) = ol;
  }
}

// Routing GEMM: acts[n, e*128+r] = x . w_route, 3-term bf16 split for ~1e-5
// accuracy; also emits norms (fp32) straight into d_out's norms section.
__global__ __launch_bounds__(256) void k_route_gemm(
    const unsigned short* __restrict__ xh, const unsigned short* __restrict__ xl,
    const unsigned short* __restrict__ wrh_t, const unsigned short* __restrict__ wrl_t,
    unsigned short* __restrict__ acts, float* __restrict__ norms_out) {
  __shared__ __align__(16) unsigned short Ah[128 * 64], Al[128 * 64];
  __shared__ __align__(16) unsigned short Bh[128 * 64], Bl[128 * 64];
  __shared__ float ssq_s[128][2];
  int tid = threadIdx.x;
  int mt = blockIdx.x, e = blockIdx.y;
  int wq = tid >> 6, lane = tid & 63;
  int wm = wq >> 1, wn = wq & 1, lg = lane >> 4, lc = lane & 15;
  f32x4 acc[4][4] = {};
  const unsigned short* ah_src = xh + (size_t)mt * 128 * 1024;
  const unsigned short* al_src = xl + (size_t)mt * 128 * 1024;
  const unsigned short* bh_src = wrh_t + (size_t)e * 128 * 1024;
  const unsigned short* bl_src = wrl_t + (size_t)e * 128 * 1024;
  for (int kt = 0; kt < 16; ++kt) {
    int k0 = kt * 64;
    stage_linear(ah_src, 1024, k0, Ah, tid);
    stage_linear(al_src, 1024, k0, Al, tid);
    stage_linear(bh_src, 1024, k0, Bh, tid);
    stage_linear(bl_src, 1024, k0, Bl, tid);
    __syncthreads();
#pragma unroll
    for (int ks = 0; ks < 2; ++ks) {
      int kb = ks * 32 + lg * 8;
      bf16x8 ahf[4], alf[4], bhf[4], blf[4];
#pragma unroll
      for (int i = 0; i < 4; ++i) {
        ahf[i] = frag_read(Ah, wm * 64 + i * 16 + lc, kb);
        alf[i] = frag_read(Al, wm * 64 + i * 16 + lc, kb);
        bhf[i] = frag_read(Bh, wn * 64 + i * 16 + lc, kb);
        blf[i] = frag_read(Bl, wn * 64 + i * 16 + lc, kb);
      }
#pragma unroll
      for (int mf = 0; mf < 4; ++mf)
#pragma unroll
        for (int nf = 0; nf < 4; ++nf) {
          acc[mf][nf] = mfma16(ahf[mf], bhf[nf], acc[mf][nf]);
          acc[mf][nf] = mfma16(alf[mf], bhf[nf], acc[mf][nf]);
          acc[mf][nf] = mfma16(ahf[mf], blf[nf], acc[mf][nf]);
        }
    }
    __syncthreads();
  }
  float ssq[4][4];
#pragma unroll
  for (int mf = 0; mf < 4; ++mf)
#pragma unroll
    for (int r = 0; r < 4; ++r) ssq[mf][r] = 0.f;
#pragma unroll
  for (int mf = 0; mf < 4; ++mf)
#pragma unroll
    for (int nf = 0; nf < 4; ++nf)
#pragma unroll
      for (int r = 0; r < 4; ++r) {
        float v = acc[mf][nf][r];
        int row = wm * 64 + mf * 16 + lg * 4 + r;
        int col = wn * 64 + nf * 16 + lc;
        acts[(size_t)(mt * 128 + row) * 1024 + e * 128 + col] = f2bf(v);
        ssq[mf][r] += v * v;
      }
#pragma unroll
  for (int mf = 0; mf < 4; ++mf)
#pragma unroll
    for (int r = 0; r < 4; ++r) {
      float s = ssq[mf][r];
      s += __shfl_xor(s, 1); s += __shfl_xor(s, 2);
      s += __shfl_xor(s, 4); s += __shfl_xor(s, 8);
      if (lc == 0) ssq_s[wm * 64 + mf * 16 + lg * 4 + r][wn] = s;
    }
  __syncthreads();
  if (tid < 128) {
    float s = ssq_s[tid][0] + ssq_s[tid][1];
    norms_out[(size_t)(mt * 128 + tid) * 8 + e] = sqrtf(s);
  }
}

// Per-token softmax + top-2 (jax tie semantics: lower index wins).
__global__ __launch_bounds__(256) void k_router(const float* __restrict__ norms,
    float* __restrict__ topw, int* __restrict__ sel,
    int* __restrict__ cnt, float* __restrict__ probsum) {
  __shared__ float ps_s[8];
  __shared__ int cnt_s[16];
  int tid = threadIdx.x;
  if (tid < 8)  ps_s[tid] = 0.f;
  if (tid < 16) cnt_s[tid] = 0;
  __syncthreads();
  int n = blockIdx.x * 256 + tid;
  float p[8], mx = -3.4e38f;
#pragma unroll
  for (int e = 0; e < 8; ++e) { p[e] = norms[(size_t)n * 8 + e]; mx = fmaxf(mx, p[e]); }
  float s = 0.f;
#pragma unroll
  for (int e = 0; e < 8; ++e) { p[e] = __expf(p[e] - mx); s += p[e]; }
  float inv = 1.f / s;
  int i1 = 0; float v1 = p[0];
#pragma unroll
  for (int e = 1; e < 8; ++e) if (p[e] > v1) { v1 = p[e]; i1 = e; }
  int i2 = -1; float v2 = -1.f;
#pragma unroll
  for (int e = 0; e < 8; ++e) if (e != i1 && p[e] > v2) { v2 = p[e]; i2 = e; }
  float wsum = v1 + v2;
  topw[n * 2 + 0] = v1 / wsum;
  topw[n * 2 + 1] = v2 / wsum;
  sel[n * 2 + 0] = i1;
  sel[n * 2 + 1] = i2;
  atomicAdd(&cnt_s[i1], 1);
  atomicAdd(&cnt_s[8 + i2], 1);
#pragma unroll
  for (int e = 0; e < 8; ++e) atomicAdd(&ps_s[e], p[e] * inv);
  __syncthreads();
  if (tid < 8)  atomicAdd(&probsum[tid], ps_s[tid]);
  if (tid < 16) atomicAdd(&cnt[tid], cnt_s[tid]);
}

// Single-thread planner: offsets, tile map (<=72 tiles/slot), bl_loss.
__global__ void k_plan(const int* __restrict__ cnt, const float* __restrict__ probsum,
                       int* __restrict__ offs, int* __restrict__ fill,
                       int4* __restrict__ tilemap, float* __restrict__ bl_out) {
  for (int k = 0; k < 2; ++k) {
    int pos = 0, t = 0;
    for (int e = 0; e < 8; ++e) {
      int c = cnt[k * 8 + e];
      offs[k * 8 + e] = pos;
      int ntl = (c + 127) >> 7;
      for (int i = 0; i < ntl; ++i) {
        int rr = c - i * 128; if (rr > 128) rr = 128;
        tilemap[k * 72 + t] = make_int4(e, pos + i * 128, rr, 0);
        ++t;
      }
      pos += c;
    }
    for (; t < 72; ++t) tilemap[k * 72 + t] = make_int4(0, pos, 0, 0);
  }
  for (int i = 0; i < 16; ++i) fill[i] = 0;
  float bl = 0.f;
  for (int e = 0; e < 8; ++e)
    bl += ((float)(cnt[e] + cnt[8 + e]) / 8192.f) * (probsum[e] / 8192.f);
  *bl_out = bl * 8.f;
}

__global__ __launch_bounds__(256) void k_fill(const int* __restrict__ sel,
    const int* __restrict__ offs, int* __restrict__ fill, int* __restrict__ list01) {
  int n = blockIdx.x * 256 + threadIdx.x;
#pragma unroll
  for (int k = 0; k < 2; ++k) {
    int e = sel[n * 2 + k];
    int pos = atomicAdd(&fill[k * 8 + e], 1);
    list01[k * 8192 + offs[k * 8 + e] + pos] = n;
  }
}

// GEMM1: h = (x@w3[e]) * silu(acts[:,e,:]@wr2h[e]) for one (tile, 128 h-cols).
__global__ __launch_bounds__(256) void k_gemm1(
    const unsigned short* __restrict__ xh, const unsigned short* __restrict__ acts,
    const unsigned short* __restrict__ w3t, const unsigned short* __restrict__ wr2h_t,
    const int* __restrict__ list, const int4* __restrict__ tilemap, int tile_lo,
    unsigned short* __restrict__ hbuf) {
  __shared__ __align__(16) unsigned short A[128 * 64], B[128 * 64];
  __shared__ int toks[128];
  int4 ent = tilemap[tile_lo + blockIdx.x];
  int e = ent.x, posbase = ent.y, rows = ent.z;
  if (rows == 0) return;
  int hbase = tilemap[tile_lo].y;
  int bn = blockIdx.y;
  int tid = threadIdx.x;
  if (tid < 128) {
    int rr = tid < rows ? tid : rows - 1;
    toks[tid] = list[posbase + rr];
  }
  __syncthreads();
  int wq = tid >> 6, lane = tid & 63;
  int wm = wq >> 1, wn = wq & 1, lg = lane >> 4, lc = lane & 15;
  f32x4 acc_a[4][4] = {};
  const unsigned short* bsrc = w3t + ((size_t)e * 4096 + bn * 128) * 1024;
  for (int kt = 0; kt < 16; ++kt) {
    int k0 = kt * 64;
    stage_gather(xh, 1024, 0, k0, toks, A, tid);
    stage_linear(bsrc, 1024, k0, B, tid);
    __syncthreads();
    mfma_block(A, B, acc_a, wm, wn, lg, lc);
    __syncthreads();
  }
  f32x4 acc_s[4][4] = {};
  const unsigned short* b2src = wr2h_t + ((size_t)e * 4096 + bn * 128) * 128;
  for (int kt = 0; kt < 2; ++kt) {
    int k0 = kt * 64;
    stage_gather(acts, 1024, (size_t)e * 128, k0, toks, A, tid);
    stage_linear(b2src, 128, k0, B, tid);
    __syncthreads();
    mfma_block(A, B, acc_s, wm, wn, lg, lc);
    __syncthreads();
  }
  size_t hrow0 = (size_t)(posbase - hbase);
#pragma unroll
  for (int mf = 0; mf < 4; ++mf)
#pragma unroll
    for (int nf = 0; nf < 4; ++nf)
#pragma unroll
      for (int r = 0; r < 4; ++r) {
        int row = wm * 64 + mf * 16 + lg * 4 + r;
        if (row < rows) {
          int col = wn * 64 + nf * 16 + lc;
          float sv = acc_s[mf][nf][r];
          float hv = acc_a[mf][nf][r] * (sv / (1.f + __expf(-sv)));
          hbuf[(hrow0 + row) * 4096 + (size_t)bn * 128 + col] = f2bf(hv);
        }
      }
}

// GEMM2: out[token, :] (+)= (h @ wh2d[e]) * topw ; slot0 stores, slot1 adds.
__global__ __launch_bounds__(256) void k_gemm2(
    const unsigned short* __restrict__ hbuf, const unsigned short* __restrict__ wh2dt,
    const int* __restrict__ list, const float* __restrict__ topw,
    const int4* __restrict__ tilemap, int tile_lo, int slot,
    float* __restrict__ out) {
  __shared__ __align__(16) unsigned short A[128 * 64], B[128 * 64];
  __shared__ int toks[128];
  __shared__ float wr_s[128];
  int4 ent = tilemap[tile_lo + blockIdx.x];
  int e = ent.x, posbase = ent.y, rows = ent.z;
  if (rows == 0) return;
  int hbase = tilemap[tile_lo].y;
  int bn = blockIdx.y;
  int tid = threadIdx.x;
  if (tid < 128) {
    int rr = tid < rows ? tid : rows - 1;
    int t = list[posbase + rr];
    toks[tid] = t;
    wr_s[tid] = topw[t * 2 + slot];
  }
  __syncthreads();
  int wq = tid >> 6, lane = tid & 63;
  int wm = wq >> 1, wn = wq & 1, lg = lane >> 4, lc = lane & 15;
  f32x4 acc[4][4] = {};
  const unsigned short* asrc = hbuf + (size_t)(posbase - hbase) * 4096;
  const unsigned short* bsrc = wh2dt + ((size_t)e * 1024 + bn * 128) * 4096;
  for (int kt = 0; kt < 64; ++kt) {
    int k0 = kt * 64;
    stage_linear(asrc, 4096, k0, A, tid);
    stage_linear(bsrc, 4096, k0, B, tid);
    __syncthreads();
    mfma_block(A, B, acc, wm, wn, lg, lc);
    __syncthreads();
  }
#pragma unroll
  for (int mf = 0; mf < 4; ++mf)
#pragma unroll
    for (int nf = 0; nf < 4; ++nf)
#pragma unroll
      for (int r = 0; r < 4; ++r) {
        int row = wm * 64 + mf * 16 + lg * 4 + r;
        if (row < rows) {
          int col = wn * 64 + nf * 16 + lc;
          float v = acc[mf][nf][r] * wr_s[row];
          size_t o = (size_t)toks[row] * 1024 + bn * 128 + col;
          if (slot == 0) out[o] = v; else out[o] += v;
        }
      }
}

// ---------------------------------------------------------------------------

extern "C" void kernel_launch(void* const* d_in, const int* in_sizes, int n_in,
                              void* d_out, int out_size, void* d_ws, size_t ws_size,
                              hipStream_t stream) {
  (void)in_sizes; (void)n_in; (void)out_size;
  const float* x      = (const float*)d_in[0];
  const float* wroute = (const float*)d_in[1];
  const float* w3     = (const float*)d_in[2];
  const float* wr2h   = (const float*)d_in[3];
  const float* wh2d   = (const float*)d_in[4];
  float* out = (float*)d_out;

  char* ws = (char*)d_ws;
  size_t off = 0;
  auto carve = [&](size_t bytes) -> void* {
    void* p = ws + off; off += (bytes + 255) & ~(size_t)255; return p;
  };
  unsigned short* xh     = (unsigned short*)carve((size_t)8192 * 1024 * 2);
  unsigned short* xl     = (unsigned short*)carve((size_t)8192 * 1024 * 2);
  unsigned short* wrh_t  = (unsigned short*)carve((size_t)8 * 128 * 1024 * 2);
  unsigned short* wrl_t  = (unsigned short*)carve((size_t)8 * 128 * 1024 * 2);
  unsigned short* w3t    = (unsigned short*)carve((size_t)8 * 4096 * 1024 * 2);
  unsigned short* wr2h_t = (unsigned short*)carve((size_t)8 * 4096 * 128 * 2);
  unsigned short* wh2dt  = (unsigned short*)carve((size_t)8 * 1024 * 4096 * 2);
  unsigned short* acts   = (unsigned short*)carve((size_t)8192 * 1024 * 2);
  int*   list01 = (int*)carve(2 * 8192 * 4);
  int*   sel    = (int*)carve(8192 * 2 * 4);
  float* topw   = (float*)carve(8192 * 2 * 4);
  int*   ctr    = (int*)carve(4096);
  int* cnt = ctr; int* fill = ctr + 16; int* offs = ctr + 32;
  float* probsum = (float*)(ctr + 48);
  int4* tilemap = (int4*)(ctr + 64);

  // h buffer: chunk the per-slot tile range if scratch is tight.
  int nchunk = 0, tpc = 0;
  for (int c = 1; c <= 8; c <<= 1) {
    int t = (72 + c - 1) / c;
    if (off + (size_t)t * 128 * 4096 * 2 <= ws_size) { nchunk = c; tpc = t; break; }
  }
  if (!nchunk) return;  // scratch too small; nothing safe to do
  unsigned short* hbuf = (unsigned short*)(ws + off);

  float* norms_out = out + 8388608;   // [N, E] fp32
  float* bl_out    = out + 8454144;   // scalar

  k_cast_x<<<2048, 256, 0, stream>>>(x, xh, xl);
  k_zero<<<1, 64, 0, stream>>>(cnt, probsum);
  k_transp<<<dim3(16 * 64, 8), 256, 0, stream>>>(w3, w3t, 1024, 4096);
  k_transp<<<dim3(64 * 16, 8), 256, 0, stream>>>(wh2d, wh2dt, 4096, 1024);
  k_transp<<<dim3(2 * 64, 8), 256, 0, stream>>>(wr2h, wr2h_t, 128, 4096);
  k_transp_split<<<dim3(16 * 2, 8), 256, 0, stream>>>(wroute, wrh_t, wrl_t, 1024, 128);
  k_route_gemm<<<dim3(64, 8), 256, 0, stream>>>(xh, xl, wrh_t, wrl_t, acts, norms_out);
  k_router<<<32, 256, 0, stream>>>(norms_out, topw, sel, cnt, probsum);
  k_plan<<<1, 1, 0, stream>>>(cnt, probsum, offs, fill, tilemap, bl_out);
  k_fill<<<32, 256, 0, stream>>>(sel, offs, fill, list01);

  for (int slot = 0; slot < 2; ++slot) {
    for (int c = 0; c < nchunk; ++c) {
      int tile_lo = c * tpc;
      int nt = (72 - tile_lo < tpc) ? (72 - tile_lo) : tpc;
      if (nt <= 0) break;
      k_gemm1<<<dim3(nt, 32), 256, 0, stream>>>(
          xh, acts, w3t, wr2h_t, list01 + slot * 8192, tilemap + slot * 72,
          tile_lo, hbuf);
      k_gemm2<<<dim3(nt, 8), 256, 0, stream>>>(
          hbuf, wh2dt, list01 + slot * 8192, topw, tilemap + slot * 72,
          tile_lo, slot, out);
    }
  }
}

// Round 2
// 889.889 us; speedup vs baseline: 1.0117x; 1.0117x over previous
//
#include <hip/hip_runtime.h>

// ---------------------------------------------------------------------------
// Routed top-2 MoE for MI355X (gfx950).  Round 2:
//  - combined slot0+slot1 tile map (up to 144 tiles), out zero + atomicAdd
//    (exactly 2 commutative fp32 adds per element -> deterministic)
//  - 2-phase prefetch (T3-minimum) in gemm1/gemm2: stage next K-step into the
//    alternate LDS buffer before computing current; 1 barrier per K-step
//  - 1D grid, bn-inner decode + bijective XCD chunk swizzle (T1) for L2 reuse
// ---------------------------------------------------------------------------

#define DEV static __device__ __forceinline__

typedef float  f32x4  __attribute__((ext_vector_type(4)));
typedef __bf16 bf16x8 __attribute__((ext_vector_type(8)));

DEV unsigned short f2bf(float f) {
  union { float f; unsigned u; } v; v.f = f;
  unsigned r = v.u + 0x7fffu + ((v.u >> 16) & 1u);   // RNE
  return (unsigned short)(r >> 16);
}
DEV float bf2f(unsigned short b) {
  union { unsigned u; float f; } v; v.u = ((unsigned)b) << 16;
  return v.f;
}

DEV void gll16(const void* g, void* l) {
  __builtin_amdgcn_global_load_lds(
      (const __attribute__((address_space(1))) unsigned int*)g,
      (__attribute__((address_space(3))) unsigned int*)l, 16, 0, 0);
}

DEV f32x4 mfma16(bf16x8 a, bf16x8 b, f32x4 c) {
  return __builtin_amdgcn_mfma_f32_16x16x32_bf16(a, b, c, 0, 0, 0);
}

// Bijective XCD chunk swizzle (m204); nwg always divisible by 8 here.
DEV int xcd_swz(int bid, int nwg) {
  int q = nwg >> 3;
  return (bid & 7) * q + (bid >> 3);
}

// Stage a [128][BK=64] bf16 tile into linear LDS; source 16B blocks XOR-
// swizzled by (row&7) so that swizzled frag reads hit spread banks.
DEV void stage_linear(const unsigned short* base, size_t pitch, int k0,
                      unsigned short* lds, int tid) {
  int wq = tid >> 6, lane = tid & 63;
#pragma unroll
  for (int i = 0; i < 4; ++i) {
    int s = wq * 256 + i * 64 + lane;     // 16B slot id, 1024 slots total
    int row = s >> 3, b = s & 7;
    int bb = b ^ (row & 7);
    const unsigned short* g = base + (size_t)row * pitch + (size_t)(k0 + bb * 8);
    gll16(g, lds + (size_t)(wq * 256 + i * 64) * 8);
  }
}

// Same, but row -> token gather through a shared-memory token list.
DEV void stage_gather(const unsigned short* base, size_t pitch, size_t colOff,
                      int k0, const int* toks, unsigned short* lds, int tid) {
  int wq = tid >> 6, lane = tid & 63;
#pragma unroll
  for (int i = 0; i < 4; ++i) {
    int s = wq * 256 + i * 64 + lane;
    int row = s >> 3, b = s & 7;
    int bb = b ^ (row & 7);
    const unsigned short* g =
        base + (size_t)toks[row] * pitch + colOff + (size_t)(k0 + bb * 8);
    gll16(g, lds + (size_t)(wq * 256 + i * 64) * 8);
  }
}

// Read one bf16x8 fragment (row, k in [kb, kb+8)) from a swizzled tile.
DEV bf16x8 frag_read(const unsigned short* lds, int row, int kb) {
  int off = row * 128 + ((kb * 2) ^ ((row & 7) << 4));
  return *(const bf16x8*)((const char*)lds + off);
}

// One BK=64 step of 16 MFMAs per wave into a 4x4 accumulator.
DEV void mfma_block(const unsigned short* A, const unsigned short* B,
                    f32x4 (&acc)[4][4], int wm, int wn, int lg, int lc) {
#pragma unroll
  for (int ks = 0; ks < 2; ++ks) {
    int kb = ks * 32 + lg * 8;
    bf16x8 af[4], bff[4];
#pragma unroll
    for (int i = 0; i < 4; ++i) {
      af[i]  = frag_read(A, wm * 64 + i * 16 + lc, kb);
      bff[i] = frag_read(B, wn * 64 + i * 16 + lc, kb);
    }
#pragma unroll
    for (int mf = 0; mf < 4; ++mf)
#pragma unroll
      for (int nf = 0; nf < 4; ++nf)
        acc[mf][nf] = mfma16(af[mf], bff[nf], acc[mf][nf]);
  }
}

// ---------------------------------------------------------------------------

__global__ __launch_bounds__(256) void k_cast_x(const float* __restrict__ x,
    unsigned short* __restrict__ xh, unsigned short* __restrict__ xl) {
  int stride = gridDim.x * blockDim.x;
  for (int i = blockIdx.x * blockDim.x + threadIdx.x; i < 8192 * 1024 / 4;
       i += stride) {
    float4 v = ((const float4*)x)[i];
    ushort4 h, l;
    h.x = f2bf(v.x); l.x = f2bf(v.x - bf2f(h.x));
    h.y = f2bf(v.y); l.y = f2bf(v.y - bf2f(h.y));
    h.z = f2bf(v.z); l.z = f2bf(v.z - bf2f(h.z));
    h.w = f2bf(v.w); l.w = f2bf(v.w - bf2f(h.w));
    ((ushort4*)xh)[i] = h;
    ((ushort4*)xl)[i] = l;
  }
}

__global__ void k_zero(int* cnt, float* probsum) {
  int t = threadIdx.x;
  if (t < 16) cnt[t] = 0;
  if (t < 8)  probsum[t] = 0.f;
}

// Transpose fp32 [E][K][N] -> bf16 [E][N][K] via 64x64 LDS tiles.
__global__ __launch_bounds__(256) void k_transp(const float* __restrict__ src,
    unsigned short* __restrict__ dst, int K, int N) {
  int ntn = N >> 6;
  int kt = blockIdx.x / ntn, nt = blockIdx.x % ntn;
  int e = blockIdx.y;
  __shared__ float tl[64][65];
  const float* s = src + (size_t)e * K * N;
  unsigned short* d = dst + (size_t)e * N * K;
  int tid = threadIdx.x;
  int c4 = (tid & 15) * 4, rr = tid >> 4;
#pragma unroll
  for (int p = 0; p < 4; ++p) {
    int row = rr + p * 16;
    float4 v = *(const float4*)(s + (size_t)(kt * 64 + row) * N + nt * 64 + c4);
    tl[row][c4] = v.x; tl[row][c4 + 1] = v.y;
    tl[row][c4 + 2] = v.z; tl[row][c4 + 3] = v.w;
  }
  __syncthreads();
#pragma unroll
  for (int p = 0; p < 4; ++p) {
    int n = rr + p * 16;
    ushort4 o;
    o.x = f2bf(tl[c4 + 0][n]); o.y = f2bf(tl[c4 + 1][n]);
    o.z = f2bf(tl[c4 + 2][n]); o.w = f2bf(tl[c4 + 3][n]);
    *(ushort4*)(d + (size_t)(nt * 64 + n) * K + kt * 64 + c4) = o;
  }
}

// Same transpose but emits hi/lo bf16 split (for w_route).
__global__ __launch_bounds__(256) void k_transp_split(const float* __restrict__ src,
    unsigned short* __restrict__ dh, unsigned short* __restrict__ dl, int K, int N) {
  int ntn = N >> 6;
  int kt = blockIdx.x / ntn, nt = blockIdx.x % ntn;
  int e = blockIdx.y;
  __shared__ float tl[64][65];
  const float* s = src + (size_t)e * K * N;
  size_t dbase = (size_t)e * N * K;
  int tid = threadIdx.x;
  int c4 = (tid & 15) * 4, rr = tid >> 4;
#pragma unroll
  for (int p = 0; p < 4; ++p) {
    int row = rr + p * 16;
    float4 v = *(const float4*)(s + (size_t)(kt * 64 + row) * N + nt * 64 + c4);
    tl[row][c4] = v.x; tl[row][c4 + 1] = v.y;
    tl[row][c4 + 2] = v.z; tl[row][c4 + 3] = v.w;
  }
  __syncthreads();
#pragma unroll
  for (int p = 0; p < 4; ++p) {
    int n = rr + p * 16;
    ushort4 oh, ol;
#pragma unroll
    for (int i = 0; i < 4; ++i) {
      float v = tl[c4 + i][n];
      unsigned short hh = f2bf(v);
      unsigned short ll = f2bf(v - bf2f(hh));
      ((unsigned short*)&oh)[i] = hh;
      ((unsigned short*)&ol)[i] = ll;
    }
    *(ushort4*)(dh + dbase + (size_t)(nt * 64 + n) * K + kt * 64 + c4) = oh;
    *(ushort4*)(dl + dbase + (size_t)(nt * 64 + n) * K + kt * 64 + c4) = ol;
  }
}

// Routing GEMM: acts[n, e*128+r] = x . w_route, 3-term bf16 split; fp32 norms.
__global__ __launch_bounds__(256) void k_route_gemm(
    const unsigned short* __restrict__ xh, const unsigned short* __restrict__ xl,
    const unsigned short* __restrict__ wrh_t, const unsigned short* __restrict__ wrl_t,
    unsigned short* __restrict__ acts, float* __restrict__ norms_out) {
  __shared__ __align__(16) unsigned short Ah[128 * 64], Al[128 * 64];
  __shared__ __align__(16) unsigned short Bh[128 * 64], Bl[128 * 64];
  __shared__ float ssq_s[128][2];
  int tid = threadIdx.x;
  int mt = blockIdx.x, e = blockIdx.y;
  int wq = tid >> 6, lane = tid & 63;
  int wm = wq >> 1, wn = wq & 1, lg = lane >> 4, lc = lane & 15;
  f32x4 acc[4][4] = {};
  const unsigned short* ah_src = xh + (size_t)mt * 128 * 1024;
  const unsigned short* al_src = xl + (size_t)mt * 128 * 1024;
  const unsigned short* bh_src = wrh_t + (size_t)e * 128 * 1024;
  const unsigned short* bl_src = wrl_t + (size_t)e * 128 * 1024;
  for (int kt = 0; kt < 16; ++kt) {
    int k0 = kt * 64;
    stage_linear(ah_src, 1024, k0, Ah, tid);
    stage_linear(al_src, 1024, k0, Al, tid);
    stage_linear(bh_src, 1024, k0, Bh, tid);
    stage_linear(bl_src, 1024, k0, Bl, tid);
    __syncthreads();
#pragma unroll
    for (int ks = 0; ks < 2; ++ks) {
      int kb = ks * 32 + lg * 8;
      bf16x8 ahf[4], alf[4], bhf[4], blf[4];
#pragma unroll
      for (int i = 0; i < 4; ++i) {
        ahf[i] = frag_read(Ah, wm * 64 + i * 16 + lc, kb);
        alf[i] = frag_read(Al, wm * 64 + i * 16 + lc, kb);
        bhf[i] = frag_read(Bh, wn * 64 + i * 16 + lc, kb);
        blf[i] = frag_read(Bl, wn * 64 + i * 16 + lc, kb);
      }
#pragma unroll
      for (int mf = 0; mf < 4; ++mf)
#pragma unroll
        for (int nf = 0; nf < 4; ++nf) {
          acc[mf][nf] = mfma16(ahf[mf], bhf[nf], acc[mf][nf]);
          acc[mf][nf] = mfma16(alf[mf], bhf[nf], acc[mf][nf]);
          acc[mf][nf] = mfma16(ahf[mf], blf[nf], acc[mf][nf]);
        }
    }
    __syncthreads();
  }
  float ssq[4][4];
#pragma unroll
  for (int mf = 0; mf < 4; ++mf)
#pragma unroll
    for (int r = 0; r < 4; ++r) ssq[mf][r] = 0.f;
#pragma unroll
  for (int mf = 0; mf < 4; ++mf)
#pragma unroll
    for (int nf = 0; nf < 4; ++nf)
#pragma unroll
      for (int r = 0; r < 4; ++r) {
        float v = acc[mf][nf][r];
        int row = wm * 64 + mf * 16 + lg * 4 + r;
        int col = wn * 64 + nf * 16 + lc;
        acts[(size_t)(mt * 128 + row) * 1024 + e * 128 + col] = f2bf(v);
        ssq[mf][r] += v * v;
      }
#pragma unroll
  for (int mf = 0; mf < 4; ++mf)
#pragma unroll
    for (int r = 0; r < 4; ++r) {
      float s = ssq[mf][r];
      s += __shfl_xor(s, 1); s += __shfl_xor(s, 2);
      s += __shfl_xor(s, 4); s += __shfl_xor(s, 8);
      if (lc == 0) ssq_s[wm * 64 + mf * 16 + lg * 4 + r][wn] = s;
    }
  __syncthreads();
  if (tid < 128) {
    float s = ssq_s[tid][0] + ssq_s[tid][1];
    norms_out[(size_t)(mt * 128 + tid) * 8 + e] = sqrtf(s);
  }
}

// Per-token softmax + top-2.
__global__ __launch_bounds__(256) void k_router(const float* __restrict__ norms,
    float* __restrict__ topw, int* __restrict__ sel,
    int* __restrict__ cnt, float* __restrict__ probsum) {
  __shared__ float ps_s[8];
  __shared__ int cnt_s[16];
  int tid = threadIdx.x;
  if (tid < 8)  ps_s[tid] = 0.f;
  if (tid < 16) cnt_s[tid] = 0;
  __syncthreads();
  int n = blockIdx.x * 256 + tid;
  float p[8], mx = -3.4e38f;
#pragma unroll
  for (int e = 0; e < 8; ++e) { p[e] = norms[(size_t)n * 8 + e]; mx = fmaxf(mx, p[e]); }
  float s = 0.f;
#pragma unroll
  for (int e = 0; e < 8; ++e) { p[e] = __expf(p[e] - mx); s += p[e]; }
  float inv = 1.f / s;
  int i1 = 0; float v1 = p[0];
#pragma unroll
  for (int e = 1; e < 8; ++e) if (p[e] > v1) { v1 = p[e]; i1 = e; }
  int i2 = -1; float v2 = -1.f;
#pragma unroll
  for (int e = 0; e < 8; ++e) if (e != i1 && p[e] > v2) { v2 = p[e]; i2 = e; }
  float wsum = v1 + v2;
  topw[n * 2 + 0] = v1 / wsum;
  topw[n * 2 + 1] = v2 / wsum;
  sel[n * 2 + 0] = i1;
  sel[n * 2 + 1] = i2;
  atomicAdd(&cnt_s[i1], 1);
  atomicAdd(&cnt_s[8 + i2], 1);
#pragma unroll
  for (int e = 0; e < 8; ++e) atomicAdd(&ps_s[e], p[e] * inv);
  __syncthreads();
  if (tid < 8)  atomicAdd(&probsum[tid], ps_s[tid]);
  if (tid < 16) atomicAdd(&cnt[tid], cnt_s[tid]);
}

// Planner: combined tile map (<=144 entries, both slots), offsets, bl_loss.
__global__ void k_plan(const int* __restrict__ cnt, const float* __restrict__ probsum,
                       int* __restrict__ offs, int* __restrict__ fill,
                       int4* __restrict__ tilemap, float* __restrict__ bl_out) {
  int t = 0;
  for (int k = 0; k < 2; ++k) {
    int pos = 0;
    for (int e = 0; e < 8; ++e) {
      int c = cnt[k * 8 + e];
      offs[k * 8 + e] = pos;
      int ntl = (c + 127) >> 7;
      for (int i = 0; i < ntl; ++i) {
        int rr = c - i * 128; if (rr > 128) rr = 128;
        tilemap[t] = make_int4(e, k * 8192 + pos + i * 128, rr, 0);
        ++t;
      }
      pos += c;
    }
  }
  for (; t < 144; ++t) tilemap[t] = make_int4(0, 0, 0, 0);
  for (int i = 0; i < 16; ++i) fill[i] = 0;
  float bl = 0.f;
  for (int e = 0; e < 8; ++e)
    bl += ((float)(cnt[e] + cnt[8 + e]) / 8192.f) * (probsum[e] / 8192.f);
  *bl_out = bl * 8.f;
}

__global__ __launch_bounds__(256) void k_fill(const int* __restrict__ sel,
    const float* __restrict__ topw, const int* __restrict__ offs,
    int* __restrict__ fill, int* __restrict__ list01, float* __restrict__ wlist) {
  int n = blockIdx.x * 256 + threadIdx.x;
#pragma unroll
  for (int k = 0; k < 2; ++k) {
    int e = sel[n * 2 + k];
    int pos = atomicAdd(&fill[k * 8 + e], 1);
    int idx = k * 8192 + offs[k * 8 + e] + pos;
    list01[idx] = n;
    wlist[idx] = topw[n * 2 + k];
  }
}

// GEMM1: h = (x@w3[e]) * silu(acts[:,e,:]@wr2h[e]); 2-phase prefetch.
__global__ __launch_bounds__(256) void k_gemm1(
    const unsigned short* __restrict__ xh, const unsigned short* __restrict__ acts,
    const unsigned short* __restrict__ w3t, const unsigned short* __restrict__ wr2h_t,
    const int* __restrict__ list, const int4* __restrict__ tilemap, int tile_lo,
    int nt, unsigned short* __restrict__ hbuf) {
  __shared__ __align__(16) unsigned short SA[2 * 128 * 64];
  __shared__ __align__(16) unsigned short SB[2 * 128 * 64];
  __shared__ int toks[128];
  int wg = xcd_swz(blockIdx.x, nt * 32);
  int tileIdx = wg >> 5, bn = wg & 31;
  int4 ent = tilemap[tile_lo + tileIdx];
  int e = ent.x, posbase = ent.y, rows = ent.z;
  if (rows == 0) return;
  int tid = threadIdx.x;
  if (tid < 128) {
    int rr = tid < rows ? tid : rows - 1;
    toks[tid] = list[posbase + rr];
  }
  __syncthreads();
  int wq = tid >> 6, lane = tid & 63;
  int wm = wq >> 1, wn = wq & 1, lg = lane >> 4, lc = lane & 15;
  f32x4 acc_a[4][4] = {};
  const unsigned short* bsrc = w3t + ((size_t)e * 4096 + bn * 128) * 1024;
  // main x@w3 loop, 16 K-steps, double-buffered prefetch
  stage_gather(xh, 1024, 0, 0, toks, SA, tid);
  stage_linear(bsrc, 1024, 0, SB, tid);
  __syncthreads();
  int cur = 0;
  for (int kt = 0; kt < 15; ++kt) {
    int nxt = cur ^ 1;
    stage_gather(xh, 1024, 0, (kt + 1) * 64, toks, SA + nxt * 8192, tid);
    stage_linear(bsrc, 1024, (kt + 1) * 64, SB + nxt * 8192, tid);
    mfma_block(SA + cur * 8192, SB + cur * 8192, acc_a, wm, wn, lg, lc);
    __syncthreads();
    cur = nxt;
  }
  mfma_block(SA + cur * 8192, SB + cur * 8192, acc_a, wm, wn, lg, lc);
  __syncthreads();
  // acts@wr2h (K=128): stage both K-steps at once, 1 barrier
  f32x4 acc_s[4][4] = {};
  const unsigned short* b2src = wr2h_t + ((size_t)e * 4096 + bn * 128) * 128;
  stage_gather(acts, 1024, (size_t)e * 128, 0, toks, SA, tid);
  stage_linear(b2src, 128, 0, SB, tid);
  stage_gather(acts, 1024, (size_t)e * 128, 64, toks, SA + 8192, tid);
  stage_linear(b2src, 128, 64, SB + 8192, tid);
  __syncthreads();
  mfma_block(SA, SB, acc_s, wm, wn, lg, lc);
  mfma_block(SA + 8192, SB + 8192, acc_s, wm, wn, lg, lc);
  size_t hrow0 = (size_t)tileIdx * 128;
#pragma unroll
  for (int mf = 0; mf < 4; ++mf)
#pragma unroll
    for (int nf = 0; nf < 4; ++nf)
#pragma unroll
      for (int r = 0; r < 4; ++r) {
        int row = wm * 64 + mf * 16 + lg * 4 + r;
        if (row < rows) {
          int col = wn * 64 + nf * 16 + lc;
          float sv = acc_s[mf][nf][r];
          float hv = acc_a[mf][nf][r] * (sv / (1.f + __expf(-sv)));
          hbuf[(hrow0 + row) * 4096 + (size_t)bn * 128 + col] = f2bf(hv);
        }
      }
}

// GEMM2: out[token, :] += (h @ wh2d[e]) * w; 2-phase prefetch; atomicAdd.
__global__ __launch_bounds__(256) void k_gemm2(
    const unsigned short* __restrict__ hbuf, const unsigned short* __restrict__ wh2dt,
    const int* __restrict__ list, const float* __restrict__ wlist,
    const int4* __restrict__ tilemap, int tile_lo, int nt,
    float* __restrict__ out) {
  __shared__ __align__(16) unsigned short SA[2 * 128 * 64];
  __shared__ __align__(16) unsigned short SB[2 * 128 * 64];
  __shared__ int toks[128];
  __shared__ float wr_s[128];
  int wg = xcd_swz(blockIdx.x, nt * 8);
  int tileIdx = wg >> 3, bn = wg & 7;
  int4 ent = tilemap[tile_lo + tileIdx];
  int e = ent.x, posbase = ent.y, rows = ent.z;
  if (rows == 0) return;
  int tid = threadIdx.x;
  if (tid < 128) {
    int rr = tid < rows ? tid : rows - 1;
    toks[tid] = list[posbase + rr];
    wr_s[tid] = wlist[posbase + rr];
  }
  __syncthreads();
  int wq = tid >> 6, lane = tid & 63;
  int wm = wq >> 1, wn = wq & 1, lg = lane >> 4, lc = lane & 15;
  f32x4 acc[4][4] = {};
  const unsigned short* asrc = hbuf + (size_t)tileIdx * 128 * 4096;
  const unsigned short* bsrc = wh2dt + ((size_t)e * 1024 + bn * 128) * 4096;
  stage_linear(asrc, 4096, 0, SA, tid);
  stage_linear(bsrc, 4096, 0, SB, tid);
  __syncthreads();
  int cur = 0;
  for (int kt = 0; kt < 63; ++kt) {
    int nxt = cur ^ 1;
    stage_linear(asrc, 4096, (kt + 1) * 64, SA + nxt * 8192, tid);
    stage_linear(bsrc, 4096, (kt + 1) * 64, SB + nxt * 8192, tid);
    mfma_block(SA + cur * 8192, SB + cur * 8192, acc, wm, wn, lg, lc);
    __syncthreads();
    cur = nxt;
  }
  mfma_block(SA + cur * 8192, SB + cur * 8192, acc, wm, wn, lg, lc);
#pragma unroll
  for (int mf = 0; mf < 4; ++mf)
#pragma unroll
    for (int nf = 0; nf < 4; ++nf)
#pragma unroll
      for (int r = 0; r < 4; ++r) {
        int row = wm * 64 + mf * 16 + lg * 4 + r;
        if (row < rows) {
          int col = wn * 64 + nf * 16 + lc;
          float v = acc[mf][nf][r] * wr_s[row];
          atomicAdd(out + (size_t)toks[row] * 1024 + bn * 128 + col, v);
        }
      }
}

// ---------------------------------------------------------------------------

extern "C" void kernel_launch(void* const* d_in, const int* in_sizes, int n_in,
                              void* d_out, int out_size, void* d_ws, size_t ws_size,
                              hipStream_t stream) {
  (void)in_sizes; (void)n_in; (void)out_size;
  const float* x      = (const float*)d_in[0];
  const float* wroute = (const float*)d_in[1];
  const float* w3     = (const float*)d_in[2];
  const float* wr2h   = (const float*)d_in[3];
  const float* wh2d   = (const float*)d_in[4];
  float* out = (float*)d_out;

  char* ws = (char*)d_ws;
  size_t off = 0;
  auto carve = [&](size_t bytes) -> void* {
    void* p = ws + off; off += (bytes + 255) & ~(size_t)255; return p;
  };
  unsigned short* xh     = (unsigned short*)carve((size_t)8192 * 1024 * 2);
  unsigned short* xl     = (unsigned short*)carve((size_t)8192 * 1024 * 2);
  unsigned short* wrh_t  = (unsigned short*)carve((size_t)8 * 128 * 1024 * 2);
  unsigned short* wrl_t  = (unsigned short*)carve((size_t)8 * 128 * 1024 * 2);
  unsigned short* w3t    = (unsigned short*)carve((size_t)8 * 4096 * 1024 * 2);
  unsigned short* wr2h_t = (unsigned short*)carve((size_t)8 * 4096 * 128 * 2);
  unsigned short* wh2dt  = (unsigned short*)carve((size_t)8 * 1024 * 4096 * 2);
  unsigned short* acts   = (unsigned short*)carve((size_t)8192 * 1024 * 2);
  int*   list01 = (int*)carve(2 * 8192 * 4);
  float* wlist  = (float*)carve(2 * 8192 * 4);
  int*   sel    = (int*)carve(8192 * 2 * 4);
  float* topw   = (float*)carve(8192 * 2 * 4);
  int*   ctr    = (int*)carve(8192);
  int* cnt = ctr; int* fill = ctr + 16; int* offs = ctr + 32;
  float* probsum = (float*)(ctr + 48);
  int4* tilemap = (int4*)(ctr + 64);

  // h buffer: tiles-per-chunk sized to remaining scratch (1 MiB per tile).
  size_t avail = ws_size > off ? ws_size - off : 0;
  int tpc = 0;
  const int cands[8] = {144, 72, 48, 36, 24, 18, 12, 9};
  for (int i = 0; i < 8; ++i) {
    if ((size_t)cands[i] * 128 * 4096 * 2 <= avail) { tpc = cands[i]; break; }
  }
  if (!tpc) return;
  unsigned short* hbuf = (unsigned short*)(ws + off);

  float* norms_out = out + 8388608;   // [N, E] fp32
  float* bl_out    = out + 8454144;   // scalar

  hipMemsetAsync(out, 0, (size_t)8388608 * 4, stream);
  k_cast_x<<<2048, 256, 0, stream>>>(x, xh, xl);
  k_zero<<<1, 64, 0, stream>>>(cnt, probsum);
  k_transp<<<dim3(16 * 64, 8), 256, 0, stream>>>(w3, w3t, 1024, 4096);
  k_transp<<<dim3(64 * 16, 8), 256, 0, stream>>>(wh2d, wh2dt, 4096, 1024);
  k_transp<<<dim3(2 * 64, 8), 256, 0, stream>>>(wr2h, wr2h_t, 128, 4096);
  k_transp_split<<<dim3(16 * 2, 8), 256, 0, stream>>>(wroute, wrh_t, wrl_t, 1024, 128);
  k_route_gemm<<<dim3(64, 8), 256, 0, stream>>>(xh, xl, wrh_t, wrl_t, acts, norms_out);
  k_router<<<32, 256, 0, stream>>>(norms_out, topw, sel, cnt, probsum);
  k_plan<<<1, 1, 0, stream>>>(cnt, probsum, offs, fill, tilemap, bl_out);
  k_fill<<<32, 256, 0, stream>>>(sel, topw, offs, fill, list01, wlist);

  int nchunk = (144 + tpc - 1) / tpc;
  for (int c = 0; c < nchunk; ++c) {
    int tile_lo = c * tpc;
    int nt = 144 - tile_lo < tpc ? 144 - tile_lo : tpc;
    k_gemm1<<<nt * 32, 256, 0, stream>>>(
        xh, acts, w3t, wr2h_t, list01, tilemap, tile_lo, nt, hbuf);
    k_gemm2<<<nt * 8, 256, 0, stream>>>(
        hbuf, wh2dt, list01, wlist, tilemap, tile_lo, nt, out);
  }
}